// Round 2
// baseline (6817.499 us; speedup 1.0000x reference)
//
#include <hip/hip_runtime.h>
#include <hip/hip_bf16.h>
#include <cstdint>

// Seq2Seq LSTM: B=2048, H=512, I=64, T_enc=256, T_dec=10.
// Persistent cooperative kernel: 256 WGs (1/CU), 16 independent row-chains of
// 16 WGs each, synced per step by device-scope atomic group barriers.
// Weights (10 unique 128x64 bf16 blocks = 160KB) live in LDS for the whole
// kernel; A operands stream global->VGPR; c state lives in registers.

#define B_    2048
#define H_    512
#define I_    64
#define TENC  256
#define TDEC  10
#define NP    2048          // 4*H
#define WIMG  81920         // u16 elems per nt image: 10 blk * 128 row * 64 col

typedef __bf16 bf16x8 __attribute__((ext_vector_type(8)));
typedef float  f32x4  __attribute__((ext_vector_type(4)));
typedef unsigned int   u32;
typedef unsigned short u16;

union BCV { uint4 u; bf16x8 b; };

__device__ __forceinline__ u16 f2bf_rne(float f){
  u32 b = __float_as_uint(f);
  b += 0x7FFFu + ((b >> 16) & 1u);
  return (u16)(b >> 16);
}
__device__ __forceinline__ float bf2f(u16 u){ return __uint_as_float(((u32)u) << 16); }

__device__ __forceinline__ void gl_lds16(const void* g, void* l){
  __builtin_amdgcn_global_load_lds((const __attribute__((address_space(1))) u32*)g,
                                   (__attribute__((address_space(3))) u32*)l, 16, 0, 0);
}

__device__ __forceinline__ float sigm(float x){ return 1.f / (1.f + __expf(-x)); }
__device__ __forceinline__ float tanhfast(float x){ return 1.f - 2.f / (1.f + __expf(2.f * x)); }

#define MFMA16 __builtin_amdgcn_mfma_f32_16x16x32_bf16

// ---------------------------------------------------------------------------
// Pack weights directly in the swizzled LDS-image layout, per nt:
// image[blk][row][pc*8+e] = W(blk)[n(row,nt)][ lc = (pc^(row&7))*8 + e ]
// blk: 0=Wih_hi 1=Wih_lo 2..9=Whh k-blocks. row->n: gate-interleaved perm.
// ---------------------------------------------------------------------------
__global__ __launch_bounds__(256) void pack_w_swz(
    const float* __restrict__ Wih, const float* __restrict__ Whh,
    const float* __restrict__ bih, const float* __restrict__ bhh,
    u16* __restrict__ Wswz, float* __restrict__ bias_pk)
{
  int idx = blockIdx.x * 256 + threadIdx.x;
  if (idx >= 16 * WIMG) return;
  int nt  = idx / WIMG;
  int rem = idx - nt * WIMG;
  int blk = rem >> 13;          // 128*64 = 8192 elems per block
  int r2  = rem & 8191;
  int row = r2 >> 6;
  int col = r2 & 63;
  int pc = col >> 3, e = col & 7;
  int lc = ((pc ^ (row & 7)) << 3) + e;
  int nh = row >> 6, gg = (row >> 4) & 3, jl = row & 15;
  int n = gg * H_ + ((nt * 2 + nh) << 4) + jl;
  u16 v;
  if (blk == 0) {
    v = f2bf_rne(Wih[n * 64 + lc]);
  } else if (blk == 1) {
    float w = Wih[n * 64 + lc];
    u16 h = f2bf_rne(w);
    v = f2bf_rne(w - bf2f(h));
  } else {
    v = f2bf_rne(Whh[(size_t)n * H_ + ((blk - 2) << 6) + lc]);
  }
  Wswz[idx] = v;
  if (blk == 0 && e == 0 && pc == (row & 7))
    bias_pk[nt * 128 + row] = bih[n] + bhh[n];
}

__global__ __launch_bounds__(256) void transpose_wd(const float* __restrict__ Wd,
                                                    float* __restrict__ WdT)
{
  int idx = blockIdx.x * 256 + threadIdx.x;
  if (idx >= I_ * H_) return;
  int n = idx >> 9, k = idx & 511;
  WdT[k * 64 + n] = Wd[idx];
}

// ---------------------------------------------------------------------------
__device__ __forceinline__ void load_w_image(char* smem, const u16* src, int tid){
  #pragma unroll
  for (int it = 0; it < 40; ++it)
    gl_lds16(src + it * 2048 + tid * 8, smem + it * 4096 + tid * 16);
}

__device__ __forceinline__ bf16x8 w_frag(const char* smem, int blk, int row, int c){
  int pc = c ^ (row & 7);
  return *(const bf16x8*)(smem + (blk << 14) + (row << 7) + (pc << 4));
}

__device__ __forceinline__ bf16x8 ld_bf8(const u16* p){
  BCV cv; cv.u = *(const uint4*)p; return cv.b;
}

__device__ __forceinline__ void cvt_x8(const float* p, bf16x8& hi, bf16x8& lo){
  float4 a = ((const float4*)p)[0];
  float4 b = ((const float4*)p)[1];
  float f[8] = {a.x, a.y, a.z, a.w, b.x, b.y, b.z, b.w};
  u32 hw[4], lw[4];
  #pragma unroll
  for (int e = 0; e < 4; ++e) {
    float f0 = f[e*2], f1 = f[e*2+1];
    u16 h0 = f2bf_rne(f0), h1 = f2bf_rne(f1);
    u16 l0 = f2bf_rne(f0 - bf2f(h0)), l1 = f2bf_rne(f1 - bf2f(h1));
    hw[e] = (u32)h0 | ((u32)h1 << 16);
    lw[e] = (u32)l0 | ((u32)l1 << 16);
  }
  BCV ch, cl;
  ch.u = make_uint4(hw[0], hw[1], hw[2], hw[3]);
  cl.u = make_uint4(lw[0], lw[1], lw[2], lw[3]);
  hi = ch.b; lo = cl.b;
}

__device__ __forceinline__ void gbar(u32* cptr, int& ev){
  __syncthreads();
  ++ev;
  if (threadIdx.x == 0) {
    __hip_atomic_fetch_add(cptr, 1u, __ATOMIC_RELEASE, __HIP_MEMORY_SCOPE_AGENT);
    u32 target = (u32)(ev << 4);
    while (__hip_atomic_load(cptr, __ATOMIC_ACQUIRE, __HIP_MEMORY_SCOPE_AGENT) < target) {
      __builtin_amdgcn_s_sleep(1);
    }
  }
  __syncthreads();
}

// ---------------------------------------------------------------------------
__global__ __launch_bounds__(256, 1) void lstm_persistent(
    const float* __restrict__ x,
    const u16* __restrict__ WswzE, const u16* __restrict__ WswzD,
    const float* __restrict__ biasE, const float* __restrict__ biasD,
    u16* __restrict__ hb0, u16* __restrict__ hb1,
    float* __restrict__ hf32, float* __restrict__ dout,
    const float* __restrict__ WdT, const float* __restrict__ ldb,
    const float* __restrict__ loW, const float* __restrict__ lob,
    float* __restrict__ out, u32* __restrict__ cnt)
{
  extern __shared__ char smem[];
  const int tid = threadIdx.x;
  const int bid = blockIdx.x;
  // group (mt) members share an XCD under round-robin bid->XCD mapping (perf only)
  const int mt = ((bid & 7) << 1) | ((bid >> 3) & 1);
  const int nt = bid >> 4;
  const int wid = tid >> 6, lane = tid & 63;
  const int mh = wid >> 1, nh = wid & 1;
  const int lr = lane & 15, lgp = lane >> 4;

  load_w_image(smem, WswzE + (size_t)nt * WIMG, tid);

  float bI = biasE[nt*128 + nh*64 +  0 + lr];
  float bF = biasE[nt*128 + nh*64 + 16 + lr];
  float bG = biasE[nt*128 + nh*64 + 32 + lr];
  float bO = biasE[nt*128 + nh*64 + 48 + lr];
  const int j    = ((nt * 2 + nh) << 4) + lr;      // hidden-unit index
  const int arow = mt*128 + mh*64 + lr;            // A-row base (+ mi*16)
  const int erow = mt*128 + mh*64 + lgp*4;         // epilogue row base (+ mi*16 + rr)

  float creg[16];
  #pragma unroll
  for (int q = 0; q < 16; ++q) creg[q] = 0.f;

  int ev = 0;
  __syncthreads();   // W image resident

  for (int t = 0; t < TENC + TDEC; ++t) {
    if (t == TENC) {
      __syncthreads();
      load_w_image(smem, WswzD + (size_t)nt * WIMG, tid);
      bI = biasD[nt*128 + nh*64 +  0 + lr];
      bF = biasD[nt*128 + nh*64 + 16 + lr];
      bG = biasD[nt*128 + nh*64 + 32 + lr];
      bO = biasD[nt*128 + nh*64 + 48 + lr];
      __syncthreads();
    }
    const u16* __restrict__ h_in  = (t & 1) ? hb1 : hb0;
    u16*       __restrict__ h_out = (t & 1) ? hb0 : hb1;
    const float* xs; size_t xst;
    if (t < TENC)       { xs = x + (size_t)t * 64;   xst = 16384; }
    else if (t == TENC) { xs = x + (size_t)255 * 64; xst = 16384; }
    else                { xs = dout;                 xst = 64; }

    // x fragments (global -> regs, hi/lo split); issued before the barrier
    bf16x8 xhi[2][4], xlo[2][4];
    #pragma unroll
    for (int ks = 0; ks < 2; ++ks)
      #pragma unroll
      for (int mi = 0; mi < 4; ++mi)
        cvt_x8(xs + (size_t)(arow + mi*16) * xst + ((ks*4 + lgp) << 3),
               xhi[ks][mi], xlo[ks][mi]);

    gbar(cnt + mt, ev);    // h(t-1) from siblings now visible

    f32x4 acc[4][4];
    #pragma unroll
    for (int a = 0; a < 4; ++a)
      #pragma unroll
      for (int b = 0; b < 4; ++b) acc[a][b] = (f32x4){0.f, 0.f, 0.f, 0.f};

    // ---- x K-blocks: xhi*Whi + xhi*Wlo + xlo*Whi ----
    #pragma unroll
    for (int ks = 0; ks < 2; ++ks) {
      int c = ks*4 + lgp;
      bf16x8 w0[4], w1[4];
      #pragma unroll
      for (int ni = 0; ni < 4; ++ni) {
        int row = nh*64 + ni*16 + lr;
        w0[ni] = w_frag(smem, 0, row, c);
        w1[ni] = w_frag(smem, 1, row, c);
      }
      #pragma unroll
      for (int mi = 0; mi < 4; ++mi)
        #pragma unroll
        for (int ni = 0; ni < 4; ++ni) {
          acc[mi][ni] = MFMA16(xhi[ks][mi], w0[ni], acc[mi][ni], 0, 0, 0);
          acc[mi][ni] = MFMA16(xhi[ks][mi], w1[ni], acc[mi][ni], 0, 0, 0);
          acc[mi][ni] = MFMA16(xlo[ks][mi], w0[ni], acc[mi][ni], 0, 0, 0);
        }
    }

    // ---- h K-blocks: A direct from global, W from resident LDS ----
    #pragma unroll
    for (int kbh = 0; kbh < 8; ++kbh) {
      #pragma unroll
      for (int ks = 0; ks < 2; ++ks) {
        int c = ks*4 + lgp;
        bf16x8 af[4], wf[4];
        #pragma unroll
        for (int mi = 0; mi < 4; ++mi)
          af[mi] = ld_bf8(h_in + (size_t)(arow + mi*16) * H_ + (kbh << 6) + (c << 3));
        #pragma unroll
        for (int ni = 0; ni < 4; ++ni)
          wf[ni] = w_frag(smem, 2 + kbh, nh*64 + ni*16 + lr, c);
        #pragma unroll
        for (int mi = 0; mi < 4; ++mi)
          #pragma unroll
          for (int ni = 0; ni < 4; ++ni)
            acc[mi][ni] = MFMA16(af[mi], wf[ni], acc[mi][ni], 0, 0, 0);
      }
    }

    // ---- fused LSTM cell epilogue; c lives in registers ----
    #pragma unroll
    for (int mi = 0; mi < 4; ++mi) {
      #pragma unroll
      for (int rr = 0; rr < 4; ++rr) {
        int row = erow + mi*16 + rr;
        float gi = acc[mi][0][rr] + bI;
        float gf = acc[mi][1][rr] + bF;
        float gg = acc[mi][2][rr] + bG;
        float go = acc[mi][3][rr] + bO;
        float c0 = creg[mi*4 + rr];
        float cn = sigm(gf) * c0 + sigm(gi) * tanhfast(gg);
        float hn = sigm(go) * tanhfast(cn);
        creg[mi*4 + rr] = cn;
        h_out[(size_t)row * H_ + j] = f2bf_rne(hn);
        if (t >= TENC) hf32[(size_t)row * H_ + j] = hn;
      }
    }

    // ---- decoder projections (fused) ----
    if (t >= TENC) {
      gbar(cnt + mt, ev);          // h/hf32 of this step visible group-wide
      int d = t - TENC;
      #pragma unroll
      for (int rb = 0; rb < 2; ++rb) {
        int b = mt*128 + nt*8 + wid*2 + rb;
        const float* hr = hf32 + (size_t)b * H_;
        float a2 = ldb[lane];
        #pragma unroll 4
        for (int k = 0; k < H_; k += 4) {
          float4 hv = *(const float4*)(hr + k);
          a2 += hv.x * WdT[(k    ) * 64 + lane] + hv.y * WdT[(k + 1) * 64 + lane]
              + hv.z * WdT[(k + 2) * 64 + lane] + hv.w * WdT[(k + 3) * 64 + lane];
        }
        dout[b * 64 + lane] = a2;
        float yv = a2 * loW[lane];
        #pragma unroll
        for (int off = 32; off; off >>= 1) yv += __shfl_xor(yv, off, 64);
        if (lane == 0) out[(size_t)b * TDEC + d] = yv + lob[0];
      }
      if (t < TENC + TDEC - 1) gbar(cnt + mt, ev);   // dout visible for next x
    }
  }
}

// ---------------------------------------------------------------------------
extern "C" void kernel_launch(void* const* d_in, const int* in_sizes, int n_in,
                              void* d_out, int out_size, void* d_ws, size_t ws_size,
                              hipStream_t stream)
{
  const float* x    = (const float*)d_in[0];
  const float* eWih = (const float*)d_in[1];
  const float* eWhh = (const float*)d_in[2];
  const float* ebih = (const float*)d_in[3];
  const float* ebhh = (const float*)d_in[4];
  const float* dWih = (const float*)d_in[5];
  const float* dWhh = (const float*)d_in[6];
  const float* dbih = (const float*)d_in[7];
  const float* dbhh = (const float*)d_in[8];
  const float* ldW  = (const float*)d_in[9];
  const float* ldbp = (const float*)d_in[10];
  const float* loW  = (const float*)d_in[11];
  const float* lob  = (const float*)d_in[12];
  float* out = (float*)d_out;

  char* ws = (char*)d_ws;
  size_t o = 0;
  auto alloc = [&](size_t bytes){ size_t r = o; o += (bytes + 255) & ~(size_t)255; return r; };
  u16*   WswzE = (u16*)  (ws + alloc((size_t)16 * WIMG * 2));
  u16*   WswzD = (u16*)  (ws + alloc((size_t)16 * WIMG * 2));
  float* biasE = (float*)(ws + alloc((size_t)NP * 4));
  float* biasD = (float*)(ws + alloc((size_t)NP * 4));
  float* WdT   = (float*)(ws + alloc((size_t)I_ * H_ * 4));
  u16*   hb0   = (u16*)  (ws + alloc((size_t)B_ * H_ * 2));
  u16*   hb1   = (u16*)  (ws + alloc((size_t)B_ * H_ * 2));
  float* hf32  = (float*)(ws + alloc((size_t)B_ * H_ * 4));
  float* dout  = (float*)(ws + alloc((size_t)B_ * I_ * 4));
  u32*   cnt   = (u32*)  (ws + alloc(64));
  (void)ws_size; (void)in_sizes; (void)n_in; (void)out_size;

  int packBlocks = (16 * WIMG + 255) / 256;
  pack_w_swz<<<packBlocks, 256, 0, stream>>>(eWih, eWhh, ebih, ebhh, WswzE, biasE);
  pack_w_swz<<<packBlocks, 256, 0, stream>>>(dWih, dWhh, dbih, dbhh, WswzD, biasD);
  transpose_wd<<<(I_ * H_ + 255) / 256, 256, 0, stream>>>(ldW, WdT);
  hipMemsetAsync(hb0, 0, (size_t)B_ * H_ * 2, stream);
  hipMemsetAsync(cnt, 0, 64, stream);

  static bool attr_set = false;
  if (!attr_set) {
    hipFuncSetAttribute((const void*)lstm_persistent,
                        hipFuncAttributeMaxDynamicSharedMemorySize, 163840);
    attr_set = true;
  }

  const float* xp = x;
  const u16 *we = WswzE, *wd = WswzD;
  const float *be = biasE, *bd = biasD, *wdt = WdT, *lb = ldbp, *lw = loW, *lo2 = lob;
  u16 *h0 = hb0, *h1 = hb1;
  float *hf = hf32, *dp = dout, *op = out;
  u32* cp = cnt;
  void* kargs[] = { (void*)&xp, (void*)&we, (void*)&wd, (void*)&be, (void*)&bd,
                    (void*)&h0, (void*)&h1, (void*)&hf, (void*)&dp, (void*)&wdt,
                    (void*)&lb, (void*)&lw, (void*)&lo2, (void*)&op, (void*)&cp };
  hipError_t e = hipLaunchCooperativeKernel((const void*)lstm_persistent,
                                            dim3(256), dim3(256), kargs, 163840, stream);
  if (e != hipSuccess) {
    // 256 WGs at 1/CU on 256 CUs are physically co-resident; plain launch fallback
    lstm_persistent<<<256, 256, 163840, stream>>>(xp, we, wd, be, bd, h0, h1, hf, dp,
                                                  wdt, lb, lw, lo2, op, cp);
  }
}